// Round 13
// baseline (139.048 us; speedup 1.0000x reference)
//
#include <hip/hip_runtime.h>
#include <math.h>

#define NB 32
#define CIN 32
#define DIM 32
#define KK 5
#define VALID 17
#define CVOL (VALID*VALID*VALID)   // 4913
#define RSF 36                     // row stride floats: 32 data + 4 zero gap (absorbs vb over-read)
#define ROWS 37                    // row = ih+2: rows 0,1,34,35,36 stay zero (absorb ih guard)
#define PLNW (ROWS*RSF)            // 1332 floats per plane
#define SLABF (7*PLNW)             // 9324 floats = 37296 B -> 4 blocks/CU

// ws layout (floats): [0,4000) w_eff ; [4000] B ; [4096, ...) C partials [nsplit][32][4913]

__global__ __launch_bounds__(256) void prep_kernel(const float* __restrict__ weight,
                                                   const float* __restrict__ bias,
                                                   float* __restrict__ ws) {
    int idx = blockIdx.x * 256 + threadIdx.x;
    if (idx < 4000) {
        float s = 0.f;
        #pragma unroll 8
        for (int co = 0; co < 64; ++co) s += weight[co * 4000 + idx];
        ws[idx] = s;
    }
    if (idx == 0) {
        float b = 0.f;
        for (int i = 0; i < 64; ++i) b += bias[i];
        ws[4000] = b;
    }
}

__device__ __forceinline__ void gload_lds16(const float* g, float* l) {
    __builtin_amdgcn_global_load_lds((const __attribute__((address_space(1))) void*)g,
                                     (__attribute__((address_space(3))) void*)l,
                                     16, 0, 0);
}

// Block = (split s, n, d-pair p). 128 threads: dq = tid>>6 (wave), hg = (tid>>3)&7, wq = tid&7.
// Thread outputs: d = 2p+dq; h = 2hg+hh (hg7: h14,15,16); w = 2wq+1, 2wq+2 (+ w=0 for wq==0).
// Slab f32 [pi 7][row 37][RSF 36]: pi = id-(4p-2); row = ih+2; cols 32..35 = permanent zeros.
// Inner loop is BRANCHLESS: zero rows/gap absorb all edge guards; reads are 90 ds_read_b128
// with pure immediate offsets (kd*5328 + j*144 + {0,16} bytes) off one per-thread base.
// Staging: per-row global_load_lds (lane<8, 16B/lane) -> padded rows with zero gaps kept intact.
// NOTE: no min-waves launch-bound arg — (128,4) forced VGPR=64 + scratch spill (round 10, 6x).
__global__ __launch_bounds__(128) void conv_kernel(const float* __restrict__ x,
                                                   const float* __restrict__ weff,
                                                   float* __restrict__ C,
                                                   int cpS) {
    __shared__ __align__(16) float slab[SLABF];
    const int b = blockIdx.x;
    const int s = b / (NB * 9);
    const int rem = b - s * (NB * 9);
    const int n = rem / 9;
    const int p = rem - n * 9;
    const int tid = threadIdx.x;
    const int dq = tid >> 6;          // wave index
    const int hg = (tid >> 3) & 7;
    const int wq = tid & 7;
    const int lane = tid & 63;
    const int d  = 2 * p + dq;
    const bool dok  = (d < VALID);
    const bool tall = (hg == 7);
    const bool w0t  = (wq == 0);

    // zero slab once: boundary rows, gap cols, OOB planes must read as 0
    for (int t = tid; t < SLABF / 4; t += 128) ((float4*)slab)[t] = make_float4(0.f, 0.f, 0.f, 0.f);
    __syncthreads();

    const int id0 = 4 * p - 2;
    const int cin0 = s * cpS;

    float acc[3][2] = {{0.f,0.f},{0.f,0.f},{0.f,0.f}};
    float accw0[3]  = {0.f, 0.f, 0.f};

    // per-thread read base: plane 2dq, row 4hg, col 4wq
    const float* rbase = slab + (2 * dq) * PLNW + (4 * hg) * RSF + 4 * wq;

    for (int ci = 0; ci < cpS; ++ci) {
        // stage: 7 planes x 32 rows, one global_load_lds (8 lanes x 16B) per row
        const float* xc = x + ((size_t)n * CIN + (cin0 + ci)) * (DIM * DIM * DIM);
        if (lane < 8) {
            #pragma unroll
            for (int pi = 0; pi < 7; ++pi) {
                const int id = id0 + pi;
                if (id >= 0 && id < DIM) {                    // block-uniform guard
                    const float* src = xc + (size_t)id * 1024 + lane * 4;
                    float* dst = slab + pi * PLNW + 2 * RSF;  // row index ih+2
                    for (int rr = dq; rr < 32; rr += 2)       // 16 rows per wave
                        gload_lds16(src + rr * 32, dst + rr * RSF);
                }
            }
        }
        __syncthreads();   // drains vmcnt: staged data visible

        const float* wb = weff + (cin0 + ci) * 125;
        #pragma unroll
        for (int kd = 0; kd < KK; ++kd) {
            #pragma unroll
            for (int j = 0; j < 9; ++j) {
                const float4 va = *(const float4*)(rbase + kd * PLNW + j * RSF);
                const float4 vb = *(const float4*)(rbase + kd * PLNW + j * RSF + 4);
                #pragma unroll
                for (int hh = 0; hh < 3; ++hh) {
                    const int kh = j - 2 * hh;
                    if (kh >= 0 && kh < KK) {   // compile-time per (j,hh)
                        const float w0 = wb[kd * 25 + kh * 5 + 0];
                        const float w1 = wb[kd * 25 + kh * 5 + 1];
                        const float w2 = wb[kd * 25 + kh * 5 + 2];
                        const float w3 = wb[kd * 25 + kh * 5 + 3];
                        const float w4 = wb[kd * 25 + kh * 5 + 4];
                        acc[hh][0] = fmaf(w0, va.x, acc[hh][0]);
                        acc[hh][1] = fmaf(w0, va.z, acc[hh][1]);
                        acc[hh][0] = fmaf(w1, va.y, acc[hh][0]);
                        acc[hh][1] = fmaf(w1, va.w, acc[hh][1]);
                        acc[hh][0] = fmaf(w2, va.z, acc[hh][0]);
                        acc[hh][1] = fmaf(w2, vb.x, acc[hh][1]);
                        acc[hh][0] = fmaf(w3, va.w, acc[hh][0]);
                        acc[hh][1] = fmaf(w3, vb.y, acc[hh][1]);
                        acc[hh][0] = fmaf(w4, vb.x, acc[hh][0]);
                        acc[hh][1] = fmaf(w4, vb.z, acc[hh][1]);
                        // w=0 (wq0 lanes use it; others discard): kw 2,3,4 hit iw 0,1,2
                        accw0[hh] = fmaf(w2, va.x, accw0[hh]);
                        accw0[hh] = fmaf(w3, va.y, accw0[hh]);
                        accw0[hh] = fmaf(w4, va.z, accw0[hh]);
                    }
                }
            }
        }
        __syncthreads();   // WAR: next stage overwrites slab
    }

    if (dok) {
        float* Cn = C + ((size_t)s * NB + n) * CVOL + (size_t)d * (VALID * VALID);
        #pragma unroll
        for (int hh = 0; hh < 3; ++hh) {
            if (hh < 2 || tall) {
                int h = 2 * hg + hh;
                Cn[h * VALID + 2 * wq + 1] = acc[hh][0];
                Cn[h * VALID + 2 * wq + 2] = acc[hh][1];
                if (w0t) Cn[h * VALID] = accw0[hh];
            }
        }
    }
}

// Blocks 0..863: one wave per active cell (n, i<3, j<3, k<3); lane = p1-subcell;
// fused nsplit reduction; butterfly sum. Blocks 864..988: constant fill.
__global__ __launch_bounds__(64) void pool_kernel(const float* __restrict__ C,
                                                  const float* __restrict__ wsB,
                                                  float* __restrict__ out,
                                                  int nsplit) {
    const int b = blockIdx.x;
    const int l = threadIdx.x;
    const float B = wsB[0];

    if (b < 864) {
        const int n = b / 27;
        const int cell = b - n * 27;
        const int ci = cell / 9, cj = (cell / 3) % 3, ck = cell % 3;
        float v = 0.f;
        if (l < 27) {
            const int da = l / 9, db = (l / 3) % 3, dc = l % 3;
            const int pz = 3 * ci + da, py = 3 * cj + db, px = 3 * ck + dc;
            const float* Cn = C + (size_t)n * CVOL;
            float m = -INFINITY;
            #pragma unroll
            for (int dz = 0; dz < 2; ++dz)
            #pragma unroll
            for (int dy = 0; dy < 2; ++dy)
            #pragma unroll
            for (int dx = 0; dx < 2; ++dx) {
                int z = 2 * pz + dz, y = 2 * py + dy, xx = 2 * px + dx;
                float t;
                if (z < VALID && y < VALID && xx < VALID) {
                    size_t off = ((size_t)z * VALID + y) * VALID + xx;
                    float sum = 0.f;
                    for (int ss = 0; ss < nsplit; ++ss)
                        sum += Cn[(size_t)ss * NB * CVOL + off];
                    t = sum + B;
                } else {
                    t = B;
                }
                m = fmaxf(m, t);
            }
            v = m;
        }
        #pragma unroll
        for (int off = 32; off > 0; off >>= 1) v += __shfl_xor(v, off, 64);
        if (l == 0) out[n * 1000 + ci * 100 + cj * 10 + ck] = v;
    } else {
        const int fb = b - 864;           // 0..124
        #pragma unroll
        for (int t = 0; t < 4; ++t) {
            int idx = fb * 256 + 64 * t + l;
            if (idx < 32000) {
                int r = idx % 1000;
                int i = r / 100, j = (r / 10) % 10, k = r % 10;
                if (i >= 3 || j >= 3 || k >= 3) out[idx] = 27.f * B;
            }
        }
    }
}

extern "C" void kernel_launch(void* const* d_in, const int* in_sizes, int n_in,
                              void* d_out, int out_size, void* d_ws, size_t ws_size,
                              hipStream_t stream) {
    const float* x      = (const float*)d_in[0];
    const float* weight = (const float*)d_in[1];
    const float* bias   = (const float*)d_in[2];
    float* out = (float*)d_out;
    float* ws  = (float*)d_ws;
    float* weff = ws;
    float* wsB  = ws + 4000;
    float* C    = ws + 4096;

    int nsplit = 1;
    if      (ws_size >= (size_t)(4096 + 8 * NB * CVOL) * 4) nsplit = 8;
    else if (ws_size >= (size_t)(4096 + 4 * NB * CVOL) * 4) nsplit = 4;
    else if (ws_size >= (size_t)(4096 + 2 * NB * CVOL) * 4) nsplit = 2;
    int cpS = CIN / nsplit;

    prep_kernel<<<dim3(16), dim3(256), 0, stream>>>(weight, bias, ws);
    conv_kernel<<<dim3(nsplit * NB * 9), dim3(128), 0, stream>>>(x, weff, C, cpS);
    pool_kernel<<<dim3(989), dim3(64), 0, stream>>>(C, wsB, out, nsplit);
}